// Round 3
// baseline (304.600 us; speedup 1.0000x reference)
//
#include <hip/hip_runtime.h>
#include <stddef.h>

#define IMG_N 4096

typedef float vf4 __attribute__((ext_vector_type(4)));

// 4 tiles of 64x32 output per block, walked left->right. 256 threads, 8 blocks/CU.
// LDS 5104 floats = 20,416 B.
// Per-tile phases (raw barriers, NO vmcnt drain -> t+1 prefetch stays in flight):
//   CONSUME: DWT1 from prefetch regs -> LDS; DWT2 via lane+10 shfl -> LDS
//   P2: conv7 (tid 0-127) || conv5 (128-159) || DWT3 (160-189)
//   P3: conv3 + IDWT3 + IDWT2 fused (tid 0-63)
//   P4: IDWT1 -> out, NT float4 stores
#define S_HH1   0        // 1056 (24 rows x stride 44, 40 cols used)
#define S_LH1   1056     // 1056
#define S_HL1   2112     // 1056
#define S_LL2   3168     // 240  (12 x 20)
#define S_LH2   3408     // 240
#define S_HL2   3648     // 240
#define S_HH2   3888     // 240
#define S_HH1C  4128     // 576  (16 x stride 36, 32 used)
#define S_HH2C  4704     // 160  (8 x 20, 16 used)
#define S_LL3   4864     // 60   (6 x 10)
#define S_LH3   4924
#define S_HL3   4984
#define S_HH3   5044
#define S_TOTAL 5104
#define S_LL1P  S_HH1    // 576 (16 x stride 36), written P3, read P4

// Raw barrier: LDS visibility only; prefetch global loads stay outstanding.
#define BAR() do { asm volatile("s_waitcnt lgkmcnt(0)" ::: "memory"); \
                   __builtin_amdgcn_s_barrier(); } while (0)

__global__ __launch_bounds__(256, 8) void haar_fused(
    const float* __restrict__ x,
    const float* __restrict__ w3, const float* __restrict__ b3,
    const float* __restrict__ w5, const float* __restrict__ b5,
    const float* __restrict__ w7, const float* __restrict__ b7,
    float* __restrict__ out)
{
    __shared__ __align__(16) float sm[S_TOTAL];
    const int tid = threadIdx.x;
    const int bx = blockIdx.x, by = blockIdx.y;
    const int R0 = by * 32;
    const int C0base = bx * 256;

    float* HH1  = sm + S_HH1;
    float* LH1  = sm + S_LH1;   float* HL1 = sm + S_HL1;
    float* LL2  = sm + S_LL2;   float* LH2 = sm + S_LH2;
    float* HL2  = sm + S_HL2;   float* HH2 = sm + S_HH2;
    float* HH1C = sm + S_HH1C;  float* HH2C = sm + S_HH2C;
    float* LL3  = sm + S_LL3;   float* LH3 = sm + S_LH3;
    float* HL3  = sm + S_HL3;   float* HH3 = sm + S_HH3;
    float* LL1P = sm + S_LL1P;

    // Loader mapping: 240 items = 24 L1-rows x 10 col-groups; 60 lanes/wave.
    // Item (mrow, g): halo rows 2*mrow, 2*mrow+1; halo cols 8g..8g+7.
    // Lane l and l+10 hold vertically adjacent L1 rows -> DWT2 via shfl.
    const int lane = tid & 63, wv = tid >> 6;
    const bool loader = (lane < 60);
    const int mrow = 6 * wv + lane / 10;    // 0..23
    const int g = lane % 10;                // 0..9
    const bool mtop = (((lane / 10) & 1) == 0);

    float4 pr[2][4];   // [t&1][r0c0, r0c1, r1c0, r1c1] — indices constant after unroll

    #pragma unroll 1
    for (int dummy = 0; dummy < 1; ++dummy) {}  // (no-op; keeps structure clear)

    // ---- prefetch tile 0 ----
    {
        const int C0t = C0base;
        const bool interior = (by >= 1) && (by <= 126) && (C0t >= 64) && (C0t <= 3968);
        if (loader) {
            if (interior) {
                const float* p = x + (size_t)(R0 - 8 + 2 * mrow) * IMG_N + (C0t - 8 + 8 * g);
                pr[0][0] = *(const float4*)(p);
                pr[0][1] = *(const float4*)(p + 4);
                pr[0][2] = *(const float4*)(p + IMG_N);
                pr[0][3] = *(const float4*)(p + IMG_N + 4);
            } else {
                const int gr0 = R0 - 8 + 2 * mrow, gr1 = gr0 + 1;
                const int gc = C0t - 8 + 8 * g;
                const bool r0v = (gr0 >= 0 && gr0 < IMG_N), r1v = (gr1 >= 0 && gr1 < IMG_N);
                float tv[8], bv[8];
                #pragma unroll
                for (int j = 0; j < 8; ++j) {
                    const int gcj = gc + j;
                    const bool cv = (gcj >= 0 && gcj < IMG_N);
                    tv[j] = (r0v && cv) ? x[(size_t)gr0 * IMG_N + gcj] : 0.0f;
                    bv[j] = (r1v && cv) ? x[(size_t)gr1 * IMG_N + gcj] : 0.0f;
                }
                pr[0][0] = make_float4(tv[0], tv[1], tv[2], tv[3]);
                pr[0][1] = make_float4(tv[4], tv[5], tv[6], tv[7]);
                pr[0][2] = make_float4(bv[0], bv[1], bv[2], bv[3]);
                pr[0][3] = make_float4(bv[4], bv[5], bv[6], bv[7]);
            }
        }
    }

    #pragma unroll
    for (int t = 0; t < 4; ++t) {
        const int C0t = C0base + 64 * t;

        // ==== CONSUME: DWT1 (regs -> LDS) + DWT2 (shfl -> LDS) ====
        if (loader) {
            const float4 t0 = pr[t & 1][0], t1 = pr[t & 1][1];
            const float4 c0 = pr[t & 1][2], c1 = pr[t & 1][3];
            float ll0, ll1, ll2, ll3;
            float4 lhv, hlv, hhv;
            {
                float a = t0.x, b = t0.y, c = c0.x, d = c0.y;
                ll0 = (a+b+c+d)*0.5f; lhv.x = (a+b-c-d)*0.5f;
                hlv.x = (a-b+c-d)*0.5f; hhv.x = (a-b-c+d)*0.5f;
                a = t0.z; b = t0.w; c = c0.z; d = c0.w;
                ll1 = (a+b+c+d)*0.5f; lhv.y = (a+b-c-d)*0.5f;
                hlv.y = (a-b+c-d)*0.5f; hhv.y = (a-b-c+d)*0.5f;
                a = t1.x; b = t1.y; c = c1.x; d = c1.y;
                ll2 = (a+b+c+d)*0.5f; lhv.z = (a+b-c-d)*0.5f;
                hlv.z = (a-b+c-d)*0.5f; hhv.z = (a-b-c+d)*0.5f;
                a = t1.z; b = t1.w; c = c1.z; d = c1.w;
                ll3 = (a+b+c+d)*0.5f; lhv.w = (a+b-c-d)*0.5f;
                hlv.w = (a-b+c-d)*0.5f; hhv.w = (a-b-c+d)*0.5f;
            }
            const int o = mrow * 44 + 4 * g;
            *(float4*)(LH1 + o) = lhv;
            *(float4*)(HL1 + o) = hlv;
            *(float4*)(HH1 + o) = hhv;
            // partner (lane+10) holds L1 row mrow+1; valid sources for mtop lanes
            const float pb0 = __shfl(ll0, lane + 10, 64);
            const float pb1 = __shfl(ll1, lane + 10, 64);
            const float pb2 = __shfl(ll2, lane + 10, 64);
            const float pb3 = __shfl(ll3, lane + 10, 64);
            if (mtop) {
                const int q = mrow >> 1;     // L2 row 0..11
                float2 l2ll, l2lh, l2hl, l2hh;
                float a = ll0, b = ll1, c = pb0, d = pb1;
                l2ll.x = (a+b+c+d)*0.5f; l2lh.x = (a+b-c-d)*0.5f;
                l2hl.x = (a-b+c-d)*0.5f; l2hh.x = (a-b-c+d)*0.5f;
                a = ll2; b = ll3; c = pb2; d = pb3;
                l2ll.y = (a+b+c+d)*0.5f; l2lh.y = (a+b-c-d)*0.5f;
                l2hl.y = (a-b+c-d)*0.5f; l2hh.y = (a-b-c+d)*0.5f;
                const int o2 = q * 20 + 2 * g;
                *(float2*)(LL2 + o2) = l2ll; *(float2*)(LH2 + o2) = l2lh;
                *(float2*)(HL2 + o2) = l2hl; *(float2*)(HH2 + o2) = l2hh;
            }
        }

        // ==== issue prefetch for tile t+1 (stays in flight through P2-P4) ====
        if (t < 3) {
            const int C0n = C0base + 64 * (t + 1);
            const bool interior = (by >= 1) && (by <= 126) && (C0n >= 64) && (C0n <= 3968);
            if (loader) {
                if (interior) {
                    const float* p = x + (size_t)(R0 - 8 + 2 * mrow) * IMG_N + (C0n - 8 + 8 * g);
                    pr[(t + 1) & 1][0] = *(const float4*)(p);
                    pr[(t + 1) & 1][1] = *(const float4*)(p + 4);
                    pr[(t + 1) & 1][2] = *(const float4*)(p + IMG_N);
                    pr[(t + 1) & 1][3] = *(const float4*)(p + IMG_N + 4);
                } else {
                    const int gr0 = R0 - 8 + 2 * mrow, gr1 = gr0 + 1;
                    const int gc = C0n - 8 + 8 * g;
                    const bool r0v = (gr0 >= 0 && gr0 < IMG_N), r1v = (gr1 >= 0 && gr1 < IMG_N);
                    float tv[8], bv[8];
                    #pragma unroll
                    for (int j = 0; j < 8; ++j) {
                        const int gcj = gc + j;
                        const bool cv = (gcj >= 0 && gcj < IMG_N);
                        tv[j] = (r0v && cv) ? x[(size_t)gr0 * IMG_N + gcj] : 0.0f;
                        bv[j] = (r1v && cv) ? x[(size_t)gr1 * IMG_N + gcj] : 0.0f;
                    }
                    pr[(t + 1) & 1][0] = make_float4(tv[0], tv[1], tv[2], tv[3]);
                    pr[(t + 1) & 1][1] = make_float4(tv[4], tv[5], tv[6], tv[7]);
                    pr[(t + 1) & 1][2] = make_float4(bv[0], bv[1], bv[2], bv[3]);
                    pr[(t + 1) & 1][3] = make_float4(bv[4], bv[5], bv[6], bv[7]);
                }
            }
        }
        BAR();   // B1

        // ==== P2: conv7 (0-127) || conv5 (128-159) || DWT3 (160-189) ====
        if (tid < 128) {
            const int i = tid >> 3;
            const int j0 = (tid & 7) << 2;
            const float bias = b7[0];
            float a0 = bias, a1 = bias, a2 = bias, a3 = bias;
            #pragma unroll
            for (int dy = 0; dy < 7; ++dy) {
                const float* rp = HH1 + (i + dy + 1) * 44 + j0;
                float4 A = *(const float4*)(rp);
                float4 B = *(const float4*)(rp + 4);
                float4 C = *(const float4*)(rp + 8);
                const float* wr = w7 + dy * 7;
                float q0 = wr[0], q1 = wr[1], q2 = wr[2], q3 = wr[3], q4 = wr[4],
                      q5 = wr[5], q6 = wr[6];
                a0 += q0*A.y + q1*A.z + q2*A.w + q3*B.x + q4*B.y + q5*B.z + q6*B.w;
                a1 += q0*A.z + q1*A.w + q2*B.x + q3*B.y + q4*B.z + q5*B.w + q6*C.x;
                a2 += q0*A.w + q1*B.x + q2*B.y + q3*B.z + q4*B.w + q5*C.x + q6*C.y;
                a3 += q0*B.x + q1*B.y + q2*B.z + q3*B.w + q4*C.x + q5*C.y + q6*C.z;
            }
            *(float4*)(HH1C + i * 36 + j0) = make_float4(a0, a1, a2, a3);
        } else if (tid < 160) {
            const int s = tid - 128;
            const int i = s >> 2;
            const int j0 = (s & 3) << 2;
            const float bias = b5[0];
            float a0 = bias, a1 = bias, a2 = bias, a3 = bias;
            #pragma unroll
            for (int dy = 0; dy < 5; ++dy) {
                const float* rp = HH2 + (i + dy) * 20 + j0;
                float4 A = *(const float4*)(rp);
                float4 B = *(const float4*)(rp + 4);
                const float* wr = w5 + dy * 5;
                float q0 = wr[0], q1 = wr[1], q2 = wr[2], q3 = wr[3], q4 = wr[4];
                a0 += q0*A.x + q1*A.y + q2*A.z + q3*A.w + q4*B.x;
                a1 += q0*A.y + q1*A.z + q2*A.w + q3*B.x + q4*B.y;
                a2 += q0*A.z + q1*A.w + q2*B.x + q3*B.y + q4*B.z;
                a3 += q0*A.w + q1*B.x + q2*B.y + q3*B.z + q4*B.w;
            }
            *(float4*)(HH2C + i * 20 + j0) = make_float4(a0, a1, a2, a3);
        } else if (tid < 190) {
            const int tt = tid - 160;
            const int u = tt / 5, v2 = (tt % 5) * 2;
            const float* rp = LL2 + (2 * u) * 20 + 2 * v2;
            float4 t0 = *(const float4*)(rp);
            float4 c0 = *(const float4*)(rp + 20);
            const int o = u * 10 + v2;
            *(float2*)(LL3 + o) = make_float2((t0.x + t0.y + c0.x + c0.y) * 0.5f,
                                              (t0.z + t0.w + c0.z + c0.w) * 0.5f);
            *(float2*)(LH3 + o) = make_float2((t0.x + t0.y - c0.x - c0.y) * 0.5f,
                                              (t0.z + t0.w - c0.z - c0.w) * 0.5f);
            *(float2*)(HL3 + o) = make_float2((t0.x - t0.y + c0.x - c0.y) * 0.5f,
                                              (t0.z - t0.w + c0.z - c0.w) * 0.5f);
            *(float2*)(HH3 + o) = make_float2((t0.x - t0.y - c0.x + c0.y) * 0.5f,
                                              (t0.z - t0.w - c0.z + c0.w) * 0.5f);
        }
        BAR();   // B2

        // ==== P3: conv3 + IDWT3 + IDWT2 fused (tid 0-63) ====
        if (tid < 64) {
            const int p = tid >> 3, c = tid & 7;
            const int r = p >> 1;
            const float sr = (p & 1) ? -1.0f : 1.0f;
            float hh = b3[0];
            #pragma unroll
            for (int dy = 0; dy < 3; ++dy) {
                const float* row = HH3 + (r + dy) * 10 + c;
                const float* wr = w3 + dy * 3;
                hh += wr[0]*row[0] + wr[1]*row[1] + wr[2]*row[2];
            }
            const int li3 = (r + 1) * 10 + (c + 1);
            const float lo3 = LL3[li3] + sr * LH3[li3];
            const float hi3 = HL3[li3] + sr * hh;
            const float v0 = (lo3 + hi3) * 0.5f;
            const float v1 = (lo3 - hi3) * 0.5f;

            const int li2 = (p + 2) * 20 + (2 * c + 2);
            float2 lh2 = *(const float2*)(LH2 + li2);
            float2 hl2 = *(const float2*)(HL2 + li2);
            float2 hc  = *(const float2*)(HH2C + p * 20 + 2 * c);
            #pragma unroll
            for (int q = 0; q < 2; ++q) {
                const float s2 = q ? -1.0f : 1.0f;
                const float lo0 = v0 + s2 * lh2.x;
                const float hi0 = hl2.x + s2 * hc.x;
                const float lo1 = v1 + s2 * lh2.y;
                const float hi1 = hl2.y + s2 * hc.y;
                *(float4*)(LL1P + (2 * p + q) * 36 + 4 * c) =
                    make_float4((lo0 + hi0) * 0.5f, (lo0 - hi0) * 0.5f,
                                (lo1 + hi1) * 0.5f, (lo1 - hi1) * 0.5f);
            }
        }
        BAR();   // B3

        // ==== P4: IDWT1 -> out (64x32), NT float4 stores ====
        #pragma unroll
        for (int k = 0; k < 2; ++k) {
            const int idx = tid + 256 * k;
            const int p = idx >> 4;
            const int c2 = (idx & 15) * 2;
            const int r = p >> 1;
            const float sr = (p & 1) ? -1.0f : 1.0f;
            const int li = (r + 4) * 44 + (c2 + 4);
            const int ci = r * 36 + c2;
            float2 llp = *(const float2*)(LL1P + ci);
            float2 lh  = *(const float2*)(LH1 + li);
            float2 hl  = *(const float2*)(HL1 + li);
            float2 hhc = *(const float2*)(HH1C + ci);
            float lo0 = llp.x + sr * lh.x;
            float hi0 = hl.x + sr * hhc.x;
            float lo1 = llp.y + sr * lh.y;
            float hi1 = hl.y + sr * hhc.y;
            vf4 o = { (lo0 + hi0) * 0.5f, (lo0 - hi0) * 0.5f,
                      (lo1 + hi1) * 0.5f, (lo1 - hi1) * 0.5f };
            __builtin_nontemporal_store(
                o, (vf4*)(out + (size_t)(R0 + p) * IMG_N + C0t + 2 * c2));
        }
        BAR();   // B4: protect LDS reuse by next tile's CONSUME
    }
}

extern "C" void kernel_launch(void* const* d_in, const int* in_sizes, int n_in,
                              void* d_out, int out_size, void* d_ws, size_t ws_size,
                              hipStream_t stream) {
    (void)in_sizes; (void)n_in; (void)out_size; (void)d_ws; (void)ws_size;
    const float* x  = (const float*)d_in[0];
    const float* w3 = (const float*)d_in[1];
    const float* b3 = (const float*)d_in[2];
    const float* w5 = (const float*)d_in[3];
    const float* b5 = (const float*)d_in[4];
    const float* w7 = (const float*)d_in[5];
    const float* b7 = (const float*)d_in[6];
    float* out = (float*)d_out;

    dim3 grid(IMG_N / 256, IMG_N / 32);    // 16 x 128 blocks, 4 tiles each
    dim3 block(256);
    haar_fused<<<grid, block, 0, stream>>>(x, w3, b3, w5, b5, w7, b7, out);
}

// Round 4
// 183.771 us; speedup vs baseline: 1.6575x; 1.6575x over previous
//
#include <hip/hip_runtime.h>
#include <stddef.h>

#define IMG_N 4096

typedef float vf4 __attribute__((ext_vector_type(4)));

// 4 tiles of 64x32 output per block, walked left->right. 256 threads.
// LDS 5104 floats = 20,416 B. __launch_bounds__(256,4): 128-VGPR budget so the
// 32-float prefetch window (bufA+bufB) lives in registers (R3 spilled at 64).
// Per-tile: CONSUME(regs->LDS DWT1+DWT2) ; issue prefetch t+1 ; BAR ; P2 ; BAR ;
//           P3 ; BAR ; P4 stores ; BAR.  Raw barriers (lgkmcnt only) keep the
//           t+1 global loads in flight across the compute phases.
#define S_HH1   0        // 1056 (24 rows x stride 44, 40 cols used)
#define S_LH1   1056     // 1056
#define S_HL1   2112     // 1056
#define S_LL2   3168     // 240  (12 x 20)
#define S_LH2   3408     // 240
#define S_HL2   3648     // 240
#define S_HH2   3888     // 240
#define S_HH1C  4128     // 576  (16 x stride 36, 32 used)
#define S_HH2C  4704     // 160  (8 x 20, 16 used)
#define S_LL3   4864     // 60   (6 x 10)
#define S_LH3   4924
#define S_HL3   4984
#define S_HH3   5044
#define S_TOTAL 5104
#define S_LL1P  S_HH1    // 576 (16 x stride 36), written P3, read P4

// Raw barrier: LDS visibility only; prefetch global loads stay outstanding.
#define BAR() do { asm volatile("s_waitcnt lgkmcnt(0)" ::: "memory"); \
                   __builtin_amdgcn_s_barrier(); } while (0)

__global__ __launch_bounds__(256, 4) void haar_fused(
    const float* __restrict__ x,
    const float* __restrict__ w3, const float* __restrict__ b3,
    const float* __restrict__ w5, const float* __restrict__ b5,
    const float* __restrict__ w7, const float* __restrict__ b7,
    float* __restrict__ out)
{
    __shared__ __align__(16) float sm[S_TOTAL];
    const int tid = threadIdx.x;
    const int bx = blockIdx.x, by = blockIdx.y;
    const int R0 = by * 32;
    const int C0base = bx * 256;

    float* HH1  = sm + S_HH1;
    float* LH1  = sm + S_LH1;   float* HL1 = sm + S_HL1;
    float* LL2  = sm + S_LL2;   float* LH2 = sm + S_LH2;
    float* HL2  = sm + S_HL2;   float* HH2 = sm + S_HH2;
    float* HH1C = sm + S_HH1C;  float* HH2C = sm + S_HH2C;
    float* LL3  = sm + S_LL3;   float* LH3 = sm + S_LH3;
    float* HL3  = sm + S_HL3;   float* HH3 = sm + S_HH3;
    float* LL1P = sm + S_LL1P;

    // Loader mapping: 240 items = 24 L1-rows x 10 col-groups; 60 lanes/wave.
    const int lane = tid & 63, wv = tid >> 6;
    const bool loader = (lane < 60);
    const int mrow = 6 * wv + lane / 10;    // 0..23
    const int g = lane % 10;                // 0..9
    const bool mtop = (((lane / 10) & 1) == 0);

    // ---- prefetch: halo rows 2*mrow..2*mrow+1, cols 8g..8g+7 of tile at C0t ----
    auto prefetch = [&](int C0t, float4 (&P)[4]) {
        if (!loader) return;
        const bool interior = (by >= 1) && (by <= 126) && (C0t >= 64) && (C0t <= 3968);
        if (interior) {
            const float* p = x + (size_t)(R0 - 8 + 2 * mrow) * IMG_N + (C0t - 8 + 8 * g);
            P[0] = *(const float4*)(p);
            P[1] = *(const float4*)(p + 4);
            P[2] = *(const float4*)(p + IMG_N);
            P[3] = *(const float4*)(p + IMG_N + 4);
        } else {
            const int gr0 = R0 - 8 + 2 * mrow, gr1 = gr0 + 1;
            const int gc = C0t - 8 + 8 * g;
            const bool r0v = (gr0 >= 0 && gr0 < IMG_N), r1v = (gr1 >= 0 && gr1 < IMG_N);
            float tv[8], bv[8];
            #pragma unroll
            for (int j = 0; j < 8; ++j) {
                const int gcj = gc + j;
                const bool cv = (gcj >= 0 && gcj < IMG_N);
                tv[j] = (r0v && cv) ? x[(size_t)gr0 * IMG_N + gcj] : 0.0f;
                bv[j] = (r1v && cv) ? x[(size_t)gr1 * IMG_N + gcj] : 0.0f;
            }
            P[0] = make_float4(tv[0], tv[1], tv[2], tv[3]);
            P[1] = make_float4(tv[4], tv[5], tv[6], tv[7]);
            P[2] = make_float4(bv[0], bv[1], bv[2], bv[3]);
            P[3] = make_float4(bv[4], bv[5], bv[6], bv[7]);
        }
    };

    // ---- consume: DWT1 (regs -> LDS) + DWT2 (lane+10 shfl -> LDS) ----
    auto consume = [&](const float4 (&P)[4]) {
        if (!loader) return;
        const float4 t0 = P[0], t1 = P[1], c0 = P[2], c1 = P[3];
        float ll0, ll1, ll2, ll3;
        float4 lhv, hlv, hhv;
        {
            float a = t0.x, b = t0.y, c = c0.x, d = c0.y;
            ll0 = (a+b+c+d)*0.5f; lhv.x = (a+b-c-d)*0.5f;
            hlv.x = (a-b+c-d)*0.5f; hhv.x = (a-b-c+d)*0.5f;
            a = t0.z; b = t0.w; c = c0.z; d = c0.w;
            ll1 = (a+b+c+d)*0.5f; lhv.y = (a+b-c-d)*0.5f;
            hlv.y = (a-b+c-d)*0.5f; hhv.y = (a-b-c+d)*0.5f;
            a = t1.x; b = t1.y; c = c1.x; d = c1.y;
            ll2 = (a+b+c+d)*0.5f; lhv.z = (a+b-c-d)*0.5f;
            hlv.z = (a-b+c-d)*0.5f; hhv.z = (a-b-c+d)*0.5f;
            a = t1.z; b = t1.w; c = c1.z; d = c1.w;
            ll3 = (a+b+c+d)*0.5f; lhv.w = (a+b-c-d)*0.5f;
            hlv.w = (a-b+c-d)*0.5f; hhv.w = (a-b-c+d)*0.5f;
        }
        const int o = mrow * 44 + 4 * g;
        *(float4*)(LH1 + o) = lhv;
        *(float4*)(HL1 + o) = hlv;
        *(float4*)(HH1 + o) = hhv;
        const float pb0 = __shfl(ll0, lane + 10, 64);
        const float pb1 = __shfl(ll1, lane + 10, 64);
        const float pb2 = __shfl(ll2, lane + 10, 64);
        const float pb3 = __shfl(ll3, lane + 10, 64);
        if (mtop) {
            const int q = mrow >> 1;     // L2 row 0..11
            float2 l2ll, l2lh, l2hl, l2hh;
            float a = ll0, b = ll1, c = pb0, d = pb1;
            l2ll.x = (a+b+c+d)*0.5f; l2lh.x = (a+b-c-d)*0.5f;
            l2hl.x = (a-b+c-d)*0.5f; l2hh.x = (a-b-c+d)*0.5f;
            a = ll2; b = ll3; c = pb2; d = pb3;
            l2ll.y = (a+b+c+d)*0.5f; l2lh.y = (a+b-c-d)*0.5f;
            l2hl.y = (a-b+c-d)*0.5f; l2hh.y = (a-b-c+d)*0.5f;
            const int o2 = q * 20 + 2 * g;
            *(float2*)(LL2 + o2) = l2ll; *(float2*)(LH2 + o2) = l2lh;
            *(float2*)(HL2 + o2) = l2hl; *(float2*)(HH2 + o2) = l2hh;
        }
    };

    // ---- P2+P3+P4 for the tile whose data is in LDS; C0t = output col base ----
    auto compute_store = [&](int C0t) {
        // P2: conv7 (0-127) || conv5 (128-159) || DWT3 (160-189)
        if (tid < 128) {
            const int i = tid >> 3;
            const int j0 = (tid & 7) << 2;
            const float bias = b7[0];
            float a0 = bias, a1 = bias, a2 = bias, a3 = bias;
            #pragma unroll
            for (int dy = 0; dy < 7; ++dy) {
                const float* rp = HH1 + (i + dy + 1) * 44 + j0;
                float4 A = *(const float4*)(rp);
                float4 B = *(const float4*)(rp + 4);
                float4 C = *(const float4*)(rp + 8);
                const float* wr = w7 + dy * 7;
                float q0 = wr[0], q1 = wr[1], q2 = wr[2], q3 = wr[3], q4 = wr[4],
                      q5 = wr[5], q6 = wr[6];
                a0 += q0*A.y + q1*A.z + q2*A.w + q3*B.x + q4*B.y + q5*B.z + q6*B.w;
                a1 += q0*A.z + q1*A.w + q2*B.x + q3*B.y + q4*B.z + q5*B.w + q6*C.x;
                a2 += q0*A.w + q1*B.x + q2*B.y + q3*B.z + q4*B.w + q5*C.x + q6*C.y;
                a3 += q0*B.x + q1*B.y + q2*B.z + q3*B.w + q4*C.x + q5*C.y + q6*C.z;
            }
            *(float4*)(HH1C + i * 36 + j0) = make_float4(a0, a1, a2, a3);
        } else if (tid < 160) {
            const int s = tid - 128;
            const int i = s >> 2;
            const int j0 = (s & 3) << 2;
            const float bias = b5[0];
            float a0 = bias, a1 = bias, a2 = bias, a3 = bias;
            #pragma unroll
            for (int dy = 0; dy < 5; ++dy) {
                const float* rp = HH2 + (i + dy) * 20 + j0;
                float4 A = *(const float4*)(rp);
                float4 B = *(const float4*)(rp + 4);
                const float* wr = w5 + dy * 5;
                float q0 = wr[0], q1 = wr[1], q2 = wr[2], q3 = wr[3], q4 = wr[4];
                a0 += q0*A.x + q1*A.y + q2*A.z + q3*A.w + q4*B.x;
                a1 += q0*A.y + q1*A.z + q2*A.w + q3*B.x + q4*B.y;
                a2 += q0*A.z + q1*A.w + q2*B.x + q3*B.y + q4*B.z;
                a3 += q0*A.w + q1*B.x + q2*B.y + q3*B.z + q4*B.w;
            }
            *(float4*)(HH2C + i * 20 + j0) = make_float4(a0, a1, a2, a3);
        } else if (tid < 190) {
            const int tt = tid - 160;
            const int u = tt / 5, v2 = (tt % 5) * 2;
            const float* rp = LL2 + (2 * u) * 20 + 2 * v2;
            float4 t0 = *(const float4*)(rp);
            float4 c0 = *(const float4*)(rp + 20);
            const int o = u * 10 + v2;
            *(float2*)(LL3 + o) = make_float2((t0.x + t0.y + c0.x + c0.y) * 0.5f,
                                              (t0.z + t0.w + c0.z + c0.w) * 0.5f);
            *(float2*)(LH3 + o) = make_float2((t0.x + t0.y - c0.x - c0.y) * 0.5f,
                                              (t0.z + t0.w - c0.z - c0.w) * 0.5f);
            *(float2*)(HL3 + o) = make_float2((t0.x - t0.y + c0.x - c0.y) * 0.5f,
                                              (t0.z - t0.w + c0.z - c0.w) * 0.5f);
            *(float2*)(HH3 + o) = make_float2((t0.x - t0.y - c0.x + c0.y) * 0.5f,
                                              (t0.z - t0.w - c0.z + c0.w) * 0.5f);
        }
        BAR();   // B2

        // P3: conv3 + IDWT3 + IDWT2 fused (tid 0-63)
        if (tid < 64) {
            const int p = tid >> 3, c = tid & 7;
            const int r = p >> 1;
            const float sr = (p & 1) ? -1.0f : 1.0f;
            float hh = b3[0];
            #pragma unroll
            for (int dy = 0; dy < 3; ++dy) {
                const float* row = HH3 + (r + dy) * 10 + c;
                const float* wr = w3 + dy * 3;
                hh += wr[0]*row[0] + wr[1]*row[1] + wr[2]*row[2];
            }
            const int li3 = (r + 1) * 10 + (c + 1);
            const float lo3 = LL3[li3] + sr * LH3[li3];
            const float hi3 = HL3[li3] + sr * hh;
            const float v0 = (lo3 + hi3) * 0.5f;
            const float v1 = (lo3 - hi3) * 0.5f;

            const int li2 = (p + 2) * 20 + (2 * c + 2);
            float2 lh2 = *(const float2*)(LH2 + li2);
            float2 hl2 = *(const float2*)(HL2 + li2);
            float2 hc  = *(const float2*)(HH2C + p * 20 + 2 * c);
            #pragma unroll
            for (int q = 0; q < 2; ++q) {
                const float s2 = q ? -1.0f : 1.0f;
                const float lo0 = v0 + s2 * lh2.x;
                const float hi0 = hl2.x + s2 * hc.x;
                const float lo1 = v1 + s2 * lh2.y;
                const float hi1 = hl2.y + s2 * hc.y;
                *(float4*)(LL1P + (2 * p + q) * 36 + 4 * c) =
                    make_float4((lo0 + hi0) * 0.5f, (lo0 - hi0) * 0.5f,
                                (lo1 + hi1) * 0.5f, (lo1 - hi1) * 0.5f);
            }
        }
        BAR();   // B3

        // P4: IDWT1 -> out (64x32), NT float4 stores
        #pragma unroll
        for (int k = 0; k < 2; ++k) {
            const int idx = tid + 256 * k;
            const int p = idx >> 4;
            const int c2 = (idx & 15) * 2;
            const int r = p >> 1;
            const float sr = (p & 1) ? -1.0f : 1.0f;
            const int li = (r + 4) * 44 + (c2 + 4);
            const int ci = r * 36 + c2;
            float2 llp = *(const float2*)(LL1P + ci);
            float2 lh  = *(const float2*)(LH1 + li);
            float2 hl  = *(const float2*)(HL1 + li);
            float2 hhc = *(const float2*)(HH1C + ci);
            float lo0 = llp.x + sr * lh.x;
            float hi0 = hl.x + sr * hhc.x;
            float lo1 = llp.y + sr * lh.y;
            float hi1 = hl.y + sr * hhc.y;
            vf4 o = { (lo0 + hi0) * 0.5f, (lo0 - hi0) * 0.5f,
                      (lo1 + hi1) * 0.5f, (lo1 - hi1) * 0.5f };
            __builtin_nontemporal_store(
                o, (vf4*)(out + (size_t)(R0 + p) * IMG_N + C0t + 2 * c2));
        }
    };

    float4 bufA[4], bufB[4];

    prefetch(C0base, bufA);
    // tile 0
    consume(bufA); prefetch(C0base + 64, bufB);
    BAR();                       // B1
    compute_store(C0base);
    BAR();                       // B4 (LDS reuse guard)
    // tile 1
    consume(bufB); prefetch(C0base + 128, bufA);
    BAR();
    compute_store(C0base + 64);
    BAR();
    // tile 2
    consume(bufA); prefetch(C0base + 192, bufB);
    BAR();
    compute_store(C0base + 128);
    BAR();
    // tile 3
    consume(bufB);
    BAR();
    compute_store(C0base + 192);
}

extern "C" void kernel_launch(void* const* d_in, const int* in_sizes, int n_in,
                              void* d_out, int out_size, void* d_ws, size_t ws_size,
                              hipStream_t stream) {
    (void)in_sizes; (void)n_in; (void)out_size; (void)d_ws; (void)ws_size;
    const float* x  = (const float*)d_in[0];
    const float* w3 = (const float*)d_in[1];
    const float* b3 = (const float*)d_in[2];
    const float* w5 = (const float*)d_in[3];
    const float* b5 = (const float*)d_in[4];
    const float* w7 = (const float*)d_in[5];
    const float* b7 = (const float*)d_in[6];
    float* out = (float*)d_out;

    dim3 grid(IMG_N / 256, IMG_N / 32);    // 16 x 128 blocks, 4 tiles each
    dim3 block(256);
    haar_fused<<<grid, block, 0, stream>>>(x, w3, b3, w5, b5, w7, b7, out);
}